// Round 2
// baseline (227.768 us; speedup 1.0000x reference)
//
#include <hip/hip_runtime.h>
#include <hip/hip_bf16.h>

// out[i, j] = x[i, j] * weight[j]
// x: 32768 x 1024 fp32, weight: 1024 fp32, out: 32768 x 1024 fp32.
// Memory-bound: 268 MB of HBM traffic, floor ~43 us at 6.3 TB/s.
//
// R1 change: ILP x4 — each thread handles 4 float4 with independent loads
// in flight (stride 256 between them keeps every wave access fully
// coalesced: lanes 0..63 of each iteration touch 64 consecutive float4).
// Column-of-float4 index is (idx & 255) since 1024/4 = 256 float4 per row.
// Weight (4 KiB) lives in L1/L2 after first touch.

__global__ __launch_bounds__(256) void diag_scale_kernel(
    const float4* __restrict__ x4,
    const float4* __restrict__ w4,   // 256 float4 = 1024 floats
    float4* __restrict__ out4,
    int n4)                          // total float4 count = 8388608
{
    // Each block covers 1024 consecutive float4 (4 per thread, stride 256).
    int base = blockIdx.x * 1024 + threadIdx.x;

    // Issue all 4 loads before any use — 4 outstanding vmem ops per thread.
    float4 xv0 = x4[base];
    float4 xv1 = x4[base + 256];
    float4 xv2 = x4[base + 512];
    float4 xv3 = x4[base + 768];

    // Same column pattern for all 4 (offsets are multiples of 256):
    float4 wv = w4[base & 255];

    float4 o0, o1, o2, o3;
    o0.x = xv0.x * wv.x; o0.y = xv0.y * wv.y; o0.z = xv0.z * wv.z; o0.w = xv0.w * wv.w;
    o1.x = xv1.x * wv.x; o1.y = xv1.y * wv.y; o1.z = xv1.z * wv.z; o1.w = xv1.w * wv.w;
    o2.x = xv2.x * wv.x; o2.y = xv2.y * wv.y; o2.z = xv2.z * wv.z; o2.w = xv2.w * wv.w;
    o3.x = xv3.x * wv.x; o3.y = xv3.y * wv.y; o3.z = xv3.z * wv.z; o3.w = xv3.w * wv.w;

    out4[base]       = o0;
    out4[base + 256] = o1;
    out4[base + 512] = o2;
    out4[base + 768] = o3;
}

extern "C" void kernel_launch(void* const* d_in, const int* in_sizes, int n_in,
                              void* d_out, int out_size, void* d_ws, size_t ws_size,
                              hipStream_t stream) {
    const float4* x4 = (const float4*)d_in[0];
    const float4* w4 = (const float4*)d_in[1];
    float4* out4 = (float4*)d_out;

    int n4 = out_size / 4;            // 32768*1024/4 = 8388608
    int grid = n4 / 1024;             // 8192 blocks, each covers 1024 float4
    diag_scale_kernel<<<grid, 256, 0, stream>>>(x4, w4, out4, n4);
}

// Round 4
// 219.564 us; speedup vs baseline: 1.0374x; 1.0374x over previous
//
#include <hip/hip_runtime.h>
#include <hip/hip_bf16.h>

// out[i, j] = x[i, j] * weight[j]
// x: 32768 x 1024 fp32, weight: 1024 fp32, out: 32768 x 1024 fp32.
// Memory-bound: 268 MB of HBM traffic, floor ~43 us at 6.3-6.8 TB/s.
//
// R0: plain float4/thread  -> bench 223.8 us (kernel component <79 us)
// R1: ILP x4               -> bench 227.8 us (neutral; TLP already saturates)
// R2/R3: nontemporal load/store on the streaming x/out paths. The builtin
//     requires a native vector type (clang ext_vector_type), not HIP's
//     float4 struct — hence the typedef. Weight (4 KiB) stays cached.

typedef float floatx4 __attribute__((ext_vector_type(4)));

__global__ __launch_bounds__(256) void diag_scale_kernel(
    const floatx4* __restrict__ x4,
    const floatx4* __restrict__ w4,  // 256 x4 = 1024 floats
    floatx4* __restrict__ out4)
{
    int idx = blockIdx.x * blockDim.x + threadIdx.x;

    floatx4 xv = __builtin_nontemporal_load(&x4[idx]);
    floatx4 wv = w4[idx & 255];      // cached: every CU reuses all 4 KiB

    floatx4 ov = xv * wv;            // elementwise on ext_vector_type

    __builtin_nontemporal_store(ov, &out4[idx]);
}

extern "C" void kernel_launch(void* const* d_in, const int* in_sizes, int n_in,
                              void* d_out, int out_size, void* d_ws, size_t ws_size,
                              hipStream_t stream) {
    const floatx4* x4 = (const floatx4*)d_in[0];
    const floatx4* w4 = (const floatx4*)d_in[1];
    floatx4* out4 = (floatx4*)d_out;

    int n4 = out_size / 4;            // 32768*1024/4 = 8388608, multiple of 256
    int grid = n4 / 256;              // 32768 blocks, exact cover (no tail)
    diag_scale_kernel<<<grid, 256, 0, stream>>>(x4, w4, out4);
}